// Round 4
// baseline (142.214 us; speedup 1.0000x reference)
//
#include <hip/hip_runtime.h>
#include <hip/hip_fp16.h>
#include <stdint.h>

// GAT: N=4096, F=512, H=8, D=64.
// score(h,i,j) = leaky(es_i + en_j); exp(leaky-M) = max(c1*u, c2*v) with
//   u=exp(en), v=exp(0.2*en), c1=exp(es-M), c2=exp(0.2*es-M)  (max picks the
//   correct piece of leaky); mask = AND with bit-packed A; fixed M per row
//   => no softmax state, j-partials combine additively (in-block LDS reduce).
//
// attn: block = 64 rows x 1 head, 8 waves = 2 row-halves x 4 j-quarters.
// NO barriers / NO LDS / NO atomics in the main loop; V, u, v read from the
// L2-resident tiled Vt; A read as 2 u64 bitmask words per wave per step.

#define NODES 4096
#define FEAT  512
#define HEADS 8
#define DH    64
#define NT    (NODES / 64)

using half2v = __attribute__((ext_vector_type(2))) _Float16;
using half8  = __attribute__((ext_vector_type(8))) _Float16;
using f32x4  = __attribute__((ext_vector_type(4))) float;

#if defined(__has_builtin)
#if __has_builtin(__builtin_amdgcn_fdot2)
#define HAS_FDOT2 1
#endif
#endif

__device__ __forceinline__ uint32_t fenc(float f) {
    uint32_t u = __float_as_uint(f);
    return (u >> 31) ? ~u : (u | 0x80000000u);
}
__device__ __forceinline__ float fdec(uint32_t e) {
    uint32_t u = (e >> 31) ? (e & 0x7FFFFFFFu) : ~e;
    return __uint_as_float(u);
}

// ---------------- prep: A->bitmask (transposed), X->f16, W -> WT[h][d][f] ----------------
#define BITS_BLOCKS 1024
__global__ void prep_kernel(const float* __restrict__ X, const float* __restrict__ W,
                            const float* __restrict__ A,
                            _Float16* __restrict__ Xh, _Float16* __restrict__ WT,
                            uint64_t* __restrict__ AbitsT) {
    if (blockIdx.x < BITS_BLOCKS) {
        // bitmask: AbitsT[wc][row] = bits of A[row][wc*64 .. +64)
        const int row  = blockIdx.x * 4 + (threadIdx.x >> 6);
        const int lane = threadIdx.x & 63;
        const float* ar = A + (size_t)row * NODES + lane;
        for (int wc = 0; wc < 64; ++wc) {
            uint64_t m = __ballot(ar[wc * 64] != 0.0f);
            if (lane == 0) AbitsT[(size_t)wc * NODES + row] = m;
        }
        return;
    }
    int idx = (blockIdx.x - BITS_BLOCKS) * blockDim.x + threadIdx.x;
    const int nx = NODES * FEAT;
    if (idx < nx) {
        Xh[idx] = (_Float16)X[idx];
    } else {
        int t = idx - nx;
        if (t < HEADS * DH * FEAT) {
            int h   = t / (DH * FEAT);
            int rem = t - h * (DH * FEAT);
            int d   = rem / FEAT;
            int f   = rem - d * FEAT;
            WT[t] = (_Float16)W[(h * FEAT + f) * DH + d];
        }
    }
}

// ---------------- feats: Vt tiled [h][jt][d][jj] f16 + e_self/u/v + enmax ----------------
__global__ __launch_bounds__(256) void feats_kernel(
    const _Float16* __restrict__ Xh, const _Float16* __restrict__ WT,
    const float* __restrict__ a_self, const float* __restrict__ a_neigh,
    _Float16* __restrict__ Vt, float* __restrict__ e_self,
    _Float16* __restrict__ u_tab, _Float16* __restrict__ v_tab,
    uint32_t* __restrict__ enmax_u) {
    const int h    = blockIdx.y;
    const int tid  = threadIdx.x;
    const int w    = tid >> 6;
    const int lane = tid & 63;
    const int l15  = lane & 15;
    const int g    = lane >> 4;
    const int bx   = blockIdx.x;
    const int n0   = bx * 64 + w * 16;

    f32x4 acc[4] = {};
    const _Float16* xb = Xh + (n0 + l15) * FEAT + g * 8;
    const _Float16* wb = WT + (h * DH + l15) * FEAT + g * 8;

#pragma unroll
    for (int kk = 0; kk < FEAT / 32; ++kk) {
        half8 b = *(const half8*)(xb + kk * 32);
#pragma unroll
        for (int mi = 0; mi < 4; ++mi) {
            half8 a = *(const half8*)(wb + mi * 16 * FEAT + kk * 32);
            acc[mi] = __builtin_amdgcn_mfma_f32_16x16x32_f16(a, b, acc[mi], 0, 0, 0);
        }
    }

    float ps = 0.f, pn = 0.f;
#pragma unroll
    for (int mi = 0; mi < 4; ++mi) {
#pragma unroll
        for (int r = 0; r < 4; ++r) {
            int d = mi * 16 + g * 4 + r;
            float v = acc[mi][r];
            Vt[((size_t)h * NT + bx) * 4096 + d * 64 + w * 16 + l15] = (_Float16)v;
            ps += v * a_self[h * DH + d];
            pn += v * a_neigh[h * DH + d];
        }
    }
    ps += __shfl_xor(ps, 16); ps += __shfl_xor(ps, 32);
    pn += __shfl_xor(pn, 16); pn += __shfl_xor(pn, 32);
    if (g == 0) {
        int n = n0 + l15;
        e_self[h * NODES + n] = ps;
        u_tab[h * NODES + n]  = (_Float16)__expf(pn);
        v_tab[h * NODES + n]  = (_Float16)__expf(0.2f * pn);
    }
    // wave-max of pn -> one atomic per wave
    float mx = pn;
    mx = fmaxf(mx, __shfl_xor(mx, 1));
    mx = fmaxf(mx, __shfl_xor(mx, 2));
    mx = fmaxf(mx, __shfl_xor(mx, 4));
    mx = fmaxf(mx, __shfl_xor(mx, 8));
    if (lane == 0) atomicMax(enmax_u + h, fenc(mx));
}

// ---------------- attn ----------------
// grid = 64 i-tiles x 8 heads = 512 blocks, 512 threads = 8 waves.
// wave w: rh = w&1 (rows rh*32..+32), jq = w>>1 (j in [jq*1024, +1024), 16 steps of 64).
__global__ __launch_bounds__(512, 4) void attn_kernel(
    const uint64_t* __restrict__ AbitsT, const _Float16* __restrict__ Vt,
    const float* __restrict__ e_self, const _Float16* __restrict__ u_tab,
    const _Float16* __restrict__ v_tab, const uint32_t* __restrict__ enmax_u,
    const float* __restrict__ bias, float* __restrict__ out) {
    __shared__ float red[2][32][66];
    __shared__ float psr[2][32];

    const int tid  = threadIdx.x;
    const int w    = tid >> 6;
    const int lane = tid & 63;
    const int l15  = lane & 15;
    const int g    = lane >> 4;
    const int rh   = w & 1;
    const int jq   = w >> 1;
    const int h    = blockIdx.x & 7;
    const int i0   = (blockIdx.x >> 3) * 64;
    const int g8   = g * 8;

    // per-row (mi) constants
    half2v c1h[2], c2h[2];
    const float em = fdec(enmax_u[h]);
#pragma unroll
    for (int mi = 0; mi < 2; ++mi) {
        float es = e_self[h * NODES + i0 + rh * 32 + mi * 16 + l15];
        float t  = es + em;
        float M  = fmaxf(t, 0.2f * t);
        _Float16 c1 = (_Float16)__expf(es - M);
        _Float16 c2 = (_Float16)__expf(0.2f * es - M);
        c1h[mi] = half2v{c1, c1};
        c2h[mi] = half2v{c2, c2};
    }

    const _Float16* ub = u_tab + h * NODES;
    const _Float16* vb = v_tab + h * NODES;
    const uint64_t* abase = AbitsT + i0 + rh * 32 + l15;
    const _Float16* vtbase = Vt + (size_t)h * NT * 4096 + (size_t)l15 * 64 + g8;

    f32x4 acc[2][4] = {};
    float psf[2] = {0.f, 0.f};
    const half2v one2 = half2v{(_Float16)1.0f, (_Float16)1.0f};

    for (int s = 0; s < 16; ++s) {
        const int jt = jq * 16 + s;          // 64-col tile index
        const int j0 = jt * 64;

        uint64_t wb0 = abase[(size_t)jt * NODES];
        uint64_t wb1 = abase[(size_t)jt * NODES + 16];

        half8 paf[2][2];
#pragma unroll
        for (int kk = 0; kk < 2; ++kk) {
            const half8 uf = *(const half8*)(ub + j0 + kk * 32 + g8);
            const half8 vf = *(const half8*)(vb + j0 + kk * 32 + g8);
            const uint32_t h0 = (uint32_t)(wb0 >> (kk * 32));
            const uint32_t h1 = (uint32_t)(wb1 >> (kk * 32));
            const uint32_t bb[2] = {(h0 >> g8) & 0xFFu, (h1 >> g8) & 0xFFu};
#pragma unroll
            for (int mi = 0; mi < 2; ++mi) {
#pragma unroll
                for (int q = 0; q < 4; ++q) {
                    half2v u2 = half2v{uf[2 * q], uf[2 * q + 1]};
                    half2v v2 = half2v{vf[2 * q], vf[2 * q + 1]};
                    half2v p2 = __builtin_elementwise_max(u2 * c1h[mi], v2 * c2h[mi]);
                    uint32_t m = ((bb[mi] >> (2 * q)) & 1u) * 0xFFFFu |
                                 ((bb[mi] >> (2 * q + 1)) & 1u) * 0xFFFF0000u;
                    uint32_t pm = __builtin_bit_cast(uint32_t, p2) & m;
                    p2 = __builtin_bit_cast(half2v, pm);
                    paf[mi][kk][2 * q]     = p2[0];
                    paf[mi][kk][2 * q + 1] = p2[1];
#ifdef HAS_FDOT2
                    psf[mi] = __builtin_amdgcn_fdot2(p2, one2, psf[mi], false);
#else
                    psf[mi] += (float)p2[0] + (float)p2[1];
#endif
                }
            }
        }

        const _Float16* vp = vtbase + (size_t)jt * 4096;
#pragma unroll
        for (int ni = 0; ni < 4; ++ni) {
#pragma unroll
            for (int kk = 0; kk < 2; ++kk) {
                const half8 vfr = *(const half8*)(vp + ni * 16 * 64 + kk * 32);
                acc[0][ni] = __builtin_amdgcn_mfma_f32_16x16x32_f16(paf[0][kk], vfr, acc[0][ni], 0, 0, 0);
                acc[1][ni] = __builtin_amdgcn_mfma_f32_16x16x32_f16(paf[1][kk], vfr, acc[1][ni], 0, 0, 0);
            }
        }
    }

    // g-reduce row sums (uniform across g afterwards)
#pragma unroll
    for (int mi = 0; mi < 2; ++mi) {
        psf[mi] += __shfl_xor(psf[mi], 16);
        psf[mi] += __shfl_xor(psf[mi], 32);
    }

    // ---- in-block reduction over jq: jq3 writes, jq2 adds, jq1 adds, jq0 finalizes ----
#pragma unroll
    for (int round = 0; round < 3; ++round) {
        const int writer = 3 - round;
        if (jq == writer) {
#pragma unroll
            for (int mi = 0; mi < 2; ++mi) {
#pragma unroll
                for (int ni = 0; ni < 4; ++ni)
#pragma unroll
                    for (int r = 0; r < 4; ++r) {
                        float* p = &red[rh][mi * 16 + g * 4 + r][ni * 16 + l15];
                        if (round == 0) *p = acc[mi][ni][r];
                        else            *p += acc[mi][ni][r];
                    }
                if (g == 0) {
                    float* q = &psr[rh][mi * 16 + l15];
                    if (round == 0) *q = psf[mi];
                    else            *q += psf[mi];
                }
            }
        }
        __syncthreads();
    }

    if (jq == 0) {
#pragma unroll
        for (int mi = 0; mi < 2; ++mi) {
            float invr[4];
#pragma unroll
            for (int r = 0; r < 4; ++r) {
                float own = __shfl(psf[mi], g * 4 + r);
                invr[r] = 1.0f / (own + psr[rh][mi * 16 + g * 4 + r]);
            }
#pragma unroll
            for (int ni = 0; ni < 4; ++ni) {
                float bb = bias[h * DH + ni * 16 + l15];
#pragma unroll
                for (int r = 0; r < 4; ++r) {
                    float v = (acc[mi][ni][r] + red[rh][mi * 16 + g * 4 + r][ni * 16 + l15]) * invr[r] + bb;
                    out[(size_t)(i0 + rh * 32 + mi * 16 + g * 4 + r) * (HEADS * DH) + h * DH + ni * 16 + l15] =
                        fmaxf(v, 0.f);
                }
            }
        }
    }
}

extern "C" void kernel_launch(void* const* d_in, const int* in_sizes, int n_in,
                              void* d_out, int out_size, void* d_ws, size_t ws_size,
                              hipStream_t stream) {
    const float* X       = (const float*)d_in[0];
    const float* A       = (const float*)d_in[1];
    const float* W       = (const float*)d_in[2];
    const float* b       = (const float*)d_in[3];
    const float* a_self  = (const float*)d_in[4];
    const float* a_neigh = (const float*)d_in[5];
    float* out = (float*)d_out;

    char* ws = (char*)d_ws;
    size_t off = 0;
    uint64_t* AbitsT = (uint64_t*)(ws + off); off += (size_t)64 * NODES * 8;          // 2 MB
    _Float16* Xh     = (_Float16*)(ws + off); off += (size_t)NODES * FEAT * 2;        // 4 MB
    _Float16* WT     = (_Float16*)(ws + off); off += (size_t)HEADS * DH * FEAT * 2;   // 512 KB
    _Float16* Vt     = (_Float16*)(ws + off); off += (size_t)HEADS * DH * NODES * 2;  // 4 MB
    float* e_self    = (float*)(ws + off);    off += (size_t)HEADS * NODES * 4;       // 128 KB
    _Float16* u_tab  = (_Float16*)(ws + off); off += (size_t)HEADS * NODES * 2;       // 64 KB
    _Float16* v_tab  = (_Float16*)(ws + off); off += (size_t)HEADS * NODES * 2;       // 64 KB
    uint32_t* enmax_u = (uint32_t*)(ws + off); off += 64;

    hipMemsetAsync(enmax_u, 0, 64, stream);

    const int prep_rest = (NODES * FEAT + HEADS * DH * FEAT + 255) / 256;
    prep_kernel<<<BITS_BLOCKS + prep_rest, 256, 0, stream>>>(X, W, A, Xh, WT, AbitsT);
    feats_kernel<<<dim3(NODES / 64, HEADS), 256, 0, stream>>>(
        Xh, WT, a_self, a_neigh, Vt, e_self, u_tab, v_tab, enmax_u);
    attn_kernel<<<(NODES / 64) * HEADS, 512, 0, stream>>>(
        AbitsT, Vt, e_self, u_tab, v_tab, enmax_u, b, out);
}